// Round 2
// baseline (747.140 us; speedup 1.0000x reference)
//
#include <hip/hip_runtime.h>

#define CIN  32
#define COUT 32

// One half-wave (32 lanes) per rulebook pair; lane = output channel.
// Feature row is broadcast by UNIFORM-ADDRESS float4 loads (all 32 lanes load
// the same 16B -> one L1 line request, hardware broadcast) instead of
// ds_bpermute shuffles, keeping the LDS pipe idle.
// Weight column W[k][:][lane] lives in 32 VGPRs, loaded once per block.
// 2-way grid-stride unroll for memory-level parallelism.
__global__ __launch_bounds__(256, 4)
void spconv_scatter(const float* __restrict__ feat,
                    const float* __restrict__ weight,
                    const int*   __restrict__ gather,
                    const int*   __restrict__ scatter,
                    float*       __restrict__ out,
                    int npair, int M)
{
    const int k    = blockIdx.y;
    const int lane = threadIdx.x & 31;   // output channel
    const int sub  = threadIdx.x >> 5;   // half-wave slot within block
    const int pairs_per_blk = blockDim.x >> 5;

    // per-lane weight column: w[i] = W[k][i][lane]
    const float* wk = weight + (size_t)k * (CIN * COUT);
    float w[CIN];
#pragma unroll
    for (int i = 0; i < CIN; ++i) w[i] = wk[i * COUT + lane];

    const int* gk = gather  + (size_t)k * npair;
    const int* sk = scatter + (size_t)k * npair;

    const int step = gridDim.x * pairs_per_blk;

    for (int p = blockIdx.x * pairs_per_blk + sub; p < npair; p += 2 * step) {
        const int p2 = p + step;
        const int s1 = sk[p];
        const int s2 = (p2 < npair) ? sk[p2] : M;

        if (s1 < M) {
            const int g = gk[p];
            const float4* fr = (const float4*)(feat + (size_t)g * CIN);
            float acc = 0.f;
#pragma unroll
            for (int c = 0; c < 8; ++c) {
                float4 f4 = fr[c];           // uniform address -> L1 broadcast
                acc = fmaf(f4.x, w[4 * c + 0], acc);
                acc = fmaf(f4.y, w[4 * c + 1], acc);
                acc = fmaf(f4.z, w[4 * c + 2], acc);
                acc = fmaf(f4.w, w[4 * c + 3], acc);
            }
            atomicAdd(&out[(size_t)s1 * COUT + lane], acc);
        }
        if (s2 < M) {
            const int g = gk[p2];
            const float4* fr = (const float4*)(feat + (size_t)g * CIN);
            float acc = 0.f;
#pragma unroll
            for (int c = 0; c < 8; ++c) {
                float4 f4 = fr[c];
                acc = fmaf(f4.x, w[4 * c + 0], acc);
                acc = fmaf(f4.y, w[4 * c + 1], acc);
                acc = fmaf(f4.z, w[4 * c + 2], acc);
                acc = fmaf(f4.w, w[4 * c + 3], acc);
            }
            atomicAdd(&out[(size_t)s2 * COUT + lane], acc);
        }
    }
}

extern "C" void kernel_launch(void* const* d_in, const int* in_sizes, int n_in,
                              void* d_out, int out_size, void* d_ws, size_t ws_size,
                              hipStream_t stream)
{
    const float* feat    = (const float*)d_in[0];
    const float* weight  = (const float*)d_in[1];
    const int*   gather  = (const int*)d_in[2];
    const int*   scatter = (const int*)d_in[3];
    float*       out     = (float*)d_out;

    const int K     = in_sizes[1] / (CIN * COUT);   // 27
    const int npair = in_sizes[2] / K;              // 150000
    const int M     = out_size / COUT;              // num_out

    // Output must be zeroed every call (harness poisons once, never restores).
    hipMemsetAsync(d_out, 0, (size_t)out_size * sizeof(float), stream);

    dim3 grid(160, K);
    spconv_scatter<<<grid, 256, 0, stream>>>(feat, weight, gather, scatter,
                                             out, npair, M);
}